// Round 1
// baseline (10934.922 us; speedup 1.0000x reference)
//
#include <hip/hip_runtime.h>
#include <math.h>

#define TT   2048
#define CC   2048
#define NB   2
#define NH   16
#define NKV  4
#define HDIM 128
#define NFFN 5632

// ============================ RMSNorm ============================
// one block per row of C=2048; 256 threads, 8 floats/thread via float4
__global__ __launch_bounds__(256) void rmsnorm_k(const float* __restrict__ x,
        const float* __restrict__ g, float* __restrict__ o)
{
    const size_t row = blockIdx.x;
    const float4* xr = (const float4*)(x + row * CC);
    float4 v0 = xr[threadIdx.x];
    float4 v1 = xr[threadIdx.x + 256];
    float s = v0.x*v0.x + v0.y*v0.y + v0.z*v0.z + v0.w*v0.w
            + v1.x*v1.x + v1.y*v1.y + v1.z*v1.z + v1.w*v1.w;
    #pragma unroll
    for (int off = 32; off; off >>= 1) s += __shfl_xor(s, off);
    __shared__ float wsum[4];
    if ((threadIdx.x & 63) == 0) wsum[threadIdx.x >> 6] = s;
    __syncthreads();
    float tot = wsum[0] + wsum[1] + wsum[2] + wsum[3];
    float scale = rsqrtf(tot * (1.0f / CC) + 1e-5f);
    const float4* gp = (const float4*)g;
    float4 g0 = gp[threadIdx.x], g1 = gp[threadIdx.x + 256];
    float4 o0, o1;
    o0.x = v0.x * scale * g0.x; o0.y = v0.y * scale * g0.y;
    o0.z = v0.z * scale * g0.z; o0.w = v0.w * scale * g0.w;
    o1.x = v1.x * scale * g1.x; o1.y = v1.y * scale * g1.y;
    o1.z = v1.z * scale * g1.z; o1.w = v1.w * scale * g1.w;
    float4* op = (float4*)(o + row * CC);
    op[threadIdx.x]       = o0;
    op[threadIdx.x + 256] = o1;
}

// ============================ GEMM (NT) ============================
// C[M,N] = A[M,K] @ W[N,K]^T (+ R).  64x64 tile, BK=16, 256 thr, 4x4/thr.
#define BM 64
#define BN 64
#define BK 16
#define LDT 68   // padded row stride (floats), keeps float4 alignment

__global__ __launch_bounds__(256) void gemm_nt(const float* __restrict__ A,
        const float* __restrict__ W, const float* __restrict__ R,
        float* __restrict__ C, int M, int N, int K)
{
    __shared__ float As[BK][LDT];
    __shared__ float Ws[BK][LDT];
    const int tid = threadIdx.x;
    const int tx = tid & 15, ty = tid >> 4;
    const int bm = blockIdx.y * BM, bn = blockIdx.x * BN;
    const int lrow = tid >> 2;          // 0..63
    const int lk   = (tid & 3) * 4;     // 0,4,8,12
    const float* Ap = A + (size_t)(bm + lrow) * K + lk;
    const float* Wp = W + (size_t)(bn + lrow) * K + lk;
    float acc[4][4] = {};
    for (int k0 = 0; k0 < K; k0 += BK) {
        float4 av = *(const float4*)(Ap + k0);
        float4 wv = *(const float4*)(Wp + k0);
        __syncthreads();
        As[lk+0][lrow] = av.x; As[lk+1][lrow] = av.y;
        As[lk+2][lrow] = av.z; As[lk+3][lrow] = av.w;
        Ws[lk+0][lrow] = wv.x; Ws[lk+1][lrow] = wv.y;
        Ws[lk+2][lrow] = wv.z; Ws[lk+3][lrow] = wv.w;
        __syncthreads();
        #pragma unroll
        for (int kk = 0; kk < BK; ++kk) {
            float4 a = *(const float4*)&As[kk][ty * 4];
            float4 b = *(const float4*)&Ws[kk][tx * 4];
            acc[0][0] += a.x*b.x; acc[0][1] += a.x*b.y; acc[0][2] += a.x*b.z; acc[0][3] += a.x*b.w;
            acc[1][0] += a.y*b.x; acc[1][1] += a.y*b.y; acc[1][2] += a.y*b.z; acc[1][3] += a.y*b.w;
            acc[2][0] += a.z*b.x; acc[2][1] += a.z*b.y; acc[2][2] += a.z*b.z; acc[2][3] += a.z*b.w;
            acc[3][0] += a.w*b.x; acc[3][1] += a.w*b.y; acc[3][2] += a.w*b.z; acc[3][3] += a.w*b.w;
        }
    }
    #pragma unroll
    for (int i = 0; i < 4; ++i) {
        const size_t r = (size_t)(bm + ty * 4 + i);
        float* Crow = C + r * N + bn + tx * 4;
        float4 out;
        out.x = acc[i][0]; out.y = acc[i][1]; out.z = acc[i][2]; out.w = acc[i][3];
        if (R != nullptr) {
            float4 rv = *(const float4*)(R + r * N + bn + tx * 4);
            out.x += rv.x; out.y += rv.y; out.z += rv.z; out.w += rv.w;
        }
        *(float4*)Crow = out;
    }
}

// ================= Fused FFN GEMM: m = silu(A@W1^T) * (A@W2^T) =================
__global__ __launch_bounds__(256) void gemm_ffn_fused(const float* __restrict__ A,
        const float* __restrict__ W1, const float* __restrict__ W2,
        float* __restrict__ Mo, int M, int N, int K)
{
    __shared__ float As [BK][LDT];
    __shared__ float W1s[BK][LDT];
    __shared__ float W2s[BK][LDT];
    const int tid = threadIdx.x;
    const int tx = tid & 15, ty = tid >> 4;
    const int bm = blockIdx.y * BM, bn = blockIdx.x * BN;
    const int lrow = tid >> 2;
    const int lk   = (tid & 3) * 4;
    const float* Ap  = A  + (size_t)(bm + lrow) * K + lk;
    const float* W1p = W1 + (size_t)(bn + lrow) * K + lk;
    const float* W2p = W2 + (size_t)(bn + lrow) * K + lk;
    float acc1[4][4] = {}, acc2[4][4] = {};
    for (int k0 = 0; k0 < K; k0 += BK) {
        float4 av = *(const float4*)(Ap  + k0);
        float4 w1 = *(const float4*)(W1p + k0);
        float4 w2 = *(const float4*)(W2p + k0);
        __syncthreads();
        As [lk+0][lrow] = av.x; As [lk+1][lrow] = av.y; As [lk+2][lrow] = av.z; As [lk+3][lrow] = av.w;
        W1s[lk+0][lrow] = w1.x; W1s[lk+1][lrow] = w1.y; W1s[lk+2][lrow] = w1.z; W1s[lk+3][lrow] = w1.w;
        W2s[lk+0][lrow] = w2.x; W2s[lk+1][lrow] = w2.y; W2s[lk+2][lrow] = w2.z; W2s[lk+3][lrow] = w2.w;
        __syncthreads();
        #pragma unroll
        for (int kk = 0; kk < BK; ++kk) {
            float4 a  = *(const float4*)&As [kk][ty * 4];
            float4 b1 = *(const float4*)&W1s[kk][tx * 4];
            float4 b2 = *(const float4*)&W2s[kk][tx * 4];
            acc1[0][0]+=a.x*b1.x; acc1[0][1]+=a.x*b1.y; acc1[0][2]+=a.x*b1.z; acc1[0][3]+=a.x*b1.w;
            acc1[1][0]+=a.y*b1.x; acc1[1][1]+=a.y*b1.y; acc1[1][2]+=a.y*b1.z; acc1[1][3]+=a.y*b1.w;
            acc1[2][0]+=a.z*b1.x; acc1[2][1]+=a.z*b1.y; acc1[2][2]+=a.z*b1.z; acc1[2][3]+=a.z*b1.w;
            acc1[3][0]+=a.w*b1.x; acc1[3][1]+=a.w*b1.y; acc1[3][2]+=a.w*b1.z; acc1[3][3]+=a.w*b1.w;
            acc2[0][0]+=a.x*b2.x; acc2[0][1]+=a.x*b2.y; acc2[0][2]+=a.x*b2.z; acc2[0][3]+=a.x*b2.w;
            acc2[1][0]+=a.y*b2.x; acc2[1][1]+=a.y*b2.y; acc2[1][2]+=a.y*b2.z; acc2[1][3]+=a.y*b2.w;
            acc2[2][0]+=a.z*b2.x; acc2[2][1]+=a.z*b2.y; acc2[2][2]+=a.z*b2.z; acc2[2][3]+=a.z*b2.w;
            acc2[3][0]+=a.w*b2.x; acc2[3][1]+=a.w*b2.y; acc2[3][2]+=a.w*b2.z; acc2[3][3]+=a.w*b2.w;
        }
    }
    #pragma unroll
    for (int i = 0; i < 4; ++i) {
        const size_t r = (size_t)(bm + ty * 4 + i);
        float4 out;
        float v1, v2;
        v1 = acc1[i][0]; v2 = acc2[i][0]; out.x = (v1 / (1.0f + __expf(-v1))) * v2;
        v1 = acc1[i][1]; v2 = acc2[i][1]; out.y = (v1 / (1.0f + __expf(-v1))) * v2;
        v1 = acc1[i][2]; v2 = acc2[i][2]; out.z = (v1 / (1.0f + __expf(-v1))) * v2;
        v1 = acc1[i][3]; v2 = acc2[i][3]; out.w = (v1 / (1.0f + __expf(-v1))) * v2;
        *(float4*)(Mo + r * N + bn + tx * 4) = out;
    }
}

// ============================ RoPE (in place) ============================
// t: (B*T, nh*128) row-major; fc: (T, 64, 2) [cos,sin]
__global__ __launch_bounds__(256) void rope_k(float* __restrict__ t,
        const float* __restrict__ fc, int nh)
{
    const int e = blockIdx.x * 256 + threadIdx.x;
    const int per_row = nh * 64;
    const int row = e / per_row;
    const int rem = e - row * per_row;
    const int hh = rem >> 6, i = rem & 63;
    const int tt = row & (TT - 1);
    const float c = fc[tt * HDIM + i * 2];
    const float s = fc[tt * HDIM + i * 2 + 1];
    float2* p = (float2*)(t + (size_t)row * (nh * HDIM) + hh * HDIM + i * 2);
    float2 v = *p;
    float2 o;
    o.x = v.x * c - v.y * s;
    o.y = v.x * s + v.y * c;
    *p = o;
}

// ============================ Attention ============================
// one block per (b,h,t) query row; scores row in LDS; two-pass softmax
__global__ __launch_bounds__(256) void attn_k(const float* __restrict__ q,
        const float* __restrict__ k, const float* __restrict__ v,
        float* __restrict__ y)
{
    const int bid = blockIdx.x;
    const int t = bid & (TT - 1);
    const int h = (bid >> 11) & (NH - 1);
    const int b = bid >> 15;
    const int g = h >> 2;                 // kv head = h / REP
    __shared__ float qs[HDIM];
    __shared__ float sc[TT];
    __shared__ float red[4];
    const float* qrow = q + ((size_t)(b * TT + t) * CC) + h * HDIM;
    if (threadIdx.x < 32) ((float4*)qs)[threadIdx.x] = ((const float4*)qrow)[threadIdx.x];
    __syncthreads();
    const float scale = 0.08838834764831845f;  // 1/sqrt(128)
    const float* kbase = k + (size_t)b * TT * (NKV * HDIM) + g * HDIM;
    float lmax = -1e30f;
    for (int j = threadIdx.x; j <= t; j += 256) {
        const float4* kr = (const float4*)(kbase + (size_t)j * (NKV * HDIM));
        float d = 0.0f;
        #pragma unroll
        for (int u = 0; u < 32; ++u) {
            float4 a  = ((const float4*)qs)[u];
            float4 bb = kr[u];
            d += a.x*bb.x + a.y*bb.y + a.z*bb.z + a.w*bb.w;
        }
        d *= scale;
        sc[j] = d;
        lmax = fmaxf(lmax, d);
    }
    #pragma unroll
    for (int off = 32; off; off >>= 1) lmax = fmaxf(lmax, __shfl_xor(lmax, off));
    if ((threadIdx.x & 63) == 0) red[threadIdx.x >> 6] = lmax;
    __syncthreads();
    const float mx = fmaxf(fmaxf(red[0], red[1]), fmaxf(red[2], red[3]));
    __syncthreads();
    float lsum = 0.0f;
    for (int j = threadIdx.x; j <= t; j += 256) {
        float e = __expf(sc[j] - mx);
        sc[j] = e;
        lsum += e;
    }
    #pragma unroll
    for (int off = 32; off; off >>= 1) lsum += __shfl_xor(lsum, off);
    if ((threadIdx.x & 63) == 0) red[threadIdx.x >> 6] = lsum;
    __syncthreads();
    const float inv = 1.0f / (red[0] + red[1] + red[2] + red[3]);
    if (threadIdx.x < HDIM) {
        const int d = threadIdx.x;
        const float* vbase = v + (size_t)b * TT * (NKV * HDIM) + g * HDIM + d;
        float acc = 0.0f;
        int j = 0;
        for (; j + 3 <= t; j += 4) {
            acc += sc[j]     * vbase[(size_t)(j)     * (NKV * HDIM)];
            acc += sc[j + 1] * vbase[(size_t)(j + 1) * (NKV * HDIM)];
            acc += sc[j + 2] * vbase[(size_t)(j + 2) * (NKV * HDIM)];
            acc += sc[j + 3] * vbase[(size_t)(j + 3) * (NKV * HDIM)];
        }
        for (; j <= t; ++j) acc += sc[j] * vbase[(size_t)j * (NKV * HDIM)];
        y[((size_t)(b * TT + t) * CC) + h * HDIM + d] = acc * inv;
    }
}

// ============================ launch ============================
extern "C" void kernel_launch(void* const* d_in, const int* in_sizes, int n_in,
                              void* d_out, int out_size, void* d_ws, size_t ws_size,
                              hipStream_t stream)
{
    (void)in_sizes; (void)n_in; (void)out_size; (void)ws_size;
    const float* x     = (const float*)d_in[0];
    const float* fc    = (const float*)d_in[1];
    const float* wq    = (const float*)d_in[2];
    const float* wk    = (const float*)d_in[3];
    const float* wv    = (const float*)d_in[4];
    const float* wo    = (const float*)d_in[5];
    const float* w1    = (const float*)d_in[6];
    const float* w2    = (const float*)d_in[7];
    const float* cproj = (const float*)d_in[8];
    const float* g1    = (const float*)d_in[9];
    const float* g2    = (const float*)d_in[10];
    float* out = (float*)d_out;
    float* ws  = (float*)d_ws;

    const int ROWS = NB * TT;                 // 4096
    // workspace layout (floats)
    const size_t o_x2 = 0;                    // 8388608
    const size_t o_h  = (size_t)ROWS * CC;    // 8388608..  (h, then h2)
    const size_t o_q  = o_h + (size_t)ROWS * CC;            // 16777216
    const size_t o_k  = o_q + (size_t)ROWS * CC;            // 25165824
    const size_t o_v  = o_k + (size_t)ROWS * NKV * HDIM;    // 27262976
    const size_t o_y  = o_v + (size_t)ROWS * NKV * HDIM;    // 29360128
    const size_t o_m  = o_q;                  // reuses q/k/v/y after attention+wo

    float* h  = ws + o_h;
    float* qb = ws + o_q;
    float* kb = ws + o_k;
    float* vb = ws + o_v;
    float* yb = ws + o_y;
    float* x2 = ws + o_x2;
    float* mb = ws + o_m;

    // 1. h = rmsnorm(x) * g1
    rmsnorm_k<<<ROWS, 256, 0, stream>>>(x, g1, h);
    // 2-4. q/k/v projections
    gemm_nt<<<dim3(CC / BN, ROWS / BM), 256, 0, stream>>>(h, wq, nullptr, qb, ROWS, CC, CC);
    gemm_nt<<<dim3((NKV * HDIM) / BN, ROWS / BM), 256, 0, stream>>>(h, wk, nullptr, kb, ROWS, NKV * HDIM, CC);
    gemm_nt<<<dim3((NKV * HDIM) / BN, ROWS / BM), 256, 0, stream>>>(h, wv, nullptr, vb, ROWS, NKV * HDIM, CC);
    // 5-6. RoPE on q and k
    rope_k<<<(ROWS * NH * 64) / 256, 256, 0, stream>>>(qb, fc, NH);
    rope_k<<<(ROWS * NKV * 64) / 256, 256, 0, stream>>>(kb, fc, NKV);
    // 7. attention
    attn_k<<<NB * NH * TT, 256, 0, stream>>>(qb, kb, vb, yb);
    // 8. x2 = x + y @ wo^T
    gemm_nt<<<dim3(CC / BN, ROWS / BM), 256, 0, stream>>>(yb, wo, x, x2, ROWS, CC, CC);
    // 9. h2 = rmsnorm(x2) * g2
    rmsnorm_k<<<ROWS, 256, 0, stream>>>(x2, g2, h);
    // 10. m = silu(h2 @ w1^T) * (h2 @ w2^T)
    gemm_ffn_fused<<<dim3(NFFN / BN, ROWS / BM), 256, 0, stream>>>(h, w1, w2, mb, ROWS, NFFN, CC);
    // 11. out = x2 + m @ cproj^T
    gemm_nt<<<dim3(CC / BN, ROWS / BM), 256, 0, stream>>>(mb, cproj, x2, out, ROWS, CC, NFFN);
}

// Round 2
// 6867.997 us; speedup vs baseline: 1.5922x; 1.5922x over previous
//
#include <hip/hip_runtime.h>
#include <math.h>

#define TT   2048
#define CC   2048
#define NB   2
#define NH   16
#define NKV  4
#define HDIM 128
#define NFFN 5632

// ============================ RMSNorm ============================
__global__ __launch_bounds__(256) void rmsnorm_k(const float* __restrict__ x,
        const float* __restrict__ g, float* __restrict__ o)
{
    const size_t row = blockIdx.x;
    const float4* xr = (const float4*)(x + row * CC);
    float4 v0 = xr[threadIdx.x];
    float4 v1 = xr[threadIdx.x + 256];
    float s = v0.x*v0.x + v0.y*v0.y + v0.z*v0.z + v0.w*v0.w
            + v1.x*v1.x + v1.y*v1.y + v1.z*v1.z + v1.w*v1.w;
    #pragma unroll
    for (int off = 32; off; off >>= 1) s += __shfl_xor(s, off);
    __shared__ float wsum[4];
    if ((threadIdx.x & 63) == 0) wsum[threadIdx.x >> 6] = s;
    __syncthreads();
    float tot = wsum[0] + wsum[1] + wsum[2] + wsum[3];
    float scale = rsqrtf(tot * (1.0f / CC) + 1e-5f);
    const float4* gp = (const float4*)g;
    float4 g0 = gp[threadIdx.x], g1 = gp[threadIdx.x + 256];
    float4 o0, o1;
    o0.x = v0.x * scale * g0.x; o0.y = v0.y * scale * g0.y;
    o0.z = v0.z * scale * g0.z; o0.w = v0.w * scale * g0.w;
    o1.x = v1.x * scale * g1.x; o1.y = v1.y * scale * g1.y;
    o1.z = v1.z * scale * g1.z; o1.w = v1.w * scale * g1.w;
    float4* op = (float4*)(o + row * CC);
    op[threadIdx.x]       = o0;
    op[threadIdx.x + 256] = o1;
}

// ============================ GEMM (NT) ============================
#define BM 64
#define BN 64
#define BK 16
#define LDT 68

__global__ __launch_bounds__(256) void gemm_nt(const float* __restrict__ A,
        const float* __restrict__ W, const float* __restrict__ R,
        float* __restrict__ C, int M, int N, int K)
{
    __shared__ float As[BK][LDT];
    __shared__ float Ws[BK][LDT];
    const int tid = threadIdx.x;
    const int tx = tid & 15, ty = tid >> 4;
    const int bm = blockIdx.y * BM, bn = blockIdx.x * BN;
    const int lrow = tid >> 2;
    const int lk   = (tid & 3) * 4;
    const float* Ap = A + (size_t)(bm + lrow) * K + lk;
    const float* Wp = W + (size_t)(bn + lrow) * K + lk;
    float acc[4][4] = {};
    for (int k0 = 0; k0 < K; k0 += BK) {
        float4 av = *(const float4*)(Ap + k0);
        float4 wv = *(const float4*)(Wp + k0);
        __syncthreads();
        As[lk+0][lrow] = av.x; As[lk+1][lrow] = av.y;
        As[lk+2][lrow] = av.z; As[lk+3][lrow] = av.w;
        Ws[lk+0][lrow] = wv.x; Ws[lk+1][lrow] = wv.y;
        Ws[lk+2][lrow] = wv.z; Ws[lk+3][lrow] = wv.w;
        __syncthreads();
        #pragma unroll
        for (int kk = 0; kk < BK; ++kk) {
            float4 a = *(const float4*)&As[kk][ty * 4];
            float4 b = *(const float4*)&Ws[kk][tx * 4];
            acc[0][0] += a.x*b.x; acc[0][1] += a.x*b.y; acc[0][2] += a.x*b.z; acc[0][3] += a.x*b.w;
            acc[1][0] += a.y*b.x; acc[1][1] += a.y*b.y; acc[1][2] += a.y*b.z; acc[1][3] += a.y*b.w;
            acc[2][0] += a.z*b.x; acc[2][1] += a.z*b.y; acc[2][2] += a.z*b.z; acc[2][3] += a.z*b.w;
            acc[3][0] += a.w*b.x; acc[3][1] += a.w*b.y; acc[3][2] += a.w*b.z; acc[3][3] += a.w*b.w;
        }
    }
    #pragma unroll
    for (int i = 0; i < 4; ++i) {
        const size_t r = (size_t)(bm + ty * 4 + i);
        float* Crow = C + r * N + bn + tx * 4;
        float4 out;
        out.x = acc[i][0]; out.y = acc[i][1]; out.z = acc[i][2]; out.w = acc[i][3];
        if (R != nullptr) {
            float4 rv = *(const float4*)(R + r * N + bn + tx * 4);
            out.x += rv.x; out.y += rv.y; out.z += rv.z; out.w += rv.w;
        }
        *(float4*)Crow = out;
    }
}

// ================= Fused FFN GEMM: m = silu(A@W1^T) * (A@W2^T) =================
__global__ __launch_bounds__(256) void gemm_ffn_fused(const float* __restrict__ A,
        const float* __restrict__ W1, const float* __restrict__ W2,
        float* __restrict__ Mo, int M, int N, int K)
{
    __shared__ float As [BK][LDT];
    __shared__ float W1s[BK][LDT];
    __shared__ float W2s[BK][LDT];
    const int tid = threadIdx.x;
    const int tx = tid & 15, ty = tid >> 4;
    const int bm = blockIdx.y * BM, bn = blockIdx.x * BN;
    const int lrow = tid >> 2;
    const int lk   = (tid & 3) * 4;
    const float* Ap  = A  + (size_t)(bm + lrow) * K + lk;
    const float* W1p = W1 + (size_t)(bn + lrow) * K + lk;
    const float* W2p = W2 + (size_t)(bn + lrow) * K + lk;
    float acc1[4][4] = {}, acc2[4][4] = {};
    for (int k0 = 0; k0 < K; k0 += BK) {
        float4 av = *(const float4*)(Ap  + k0);
        float4 w1 = *(const float4*)(W1p + k0);
        float4 w2 = *(const float4*)(W2p + k0);
        __syncthreads();
        As [lk+0][lrow] = av.x; As [lk+1][lrow] = av.y; As [lk+2][lrow] = av.z; As [lk+3][lrow] = av.w;
        W1s[lk+0][lrow] = w1.x; W1s[lk+1][lrow] = w1.y; W1s[lk+2][lrow] = w1.z; W1s[lk+3][lrow] = w1.w;
        W2s[lk+0][lrow] = w2.x; W2s[lk+1][lrow] = w2.y; W2s[lk+2][lrow] = w2.z; W2s[lk+3][lrow] = w2.w;
        __syncthreads();
        #pragma unroll
        for (int kk = 0; kk < BK; ++kk) {
            float4 a  = *(const float4*)&As [kk][ty * 4];
            float4 b1 = *(const float4*)&W1s[kk][tx * 4];
            float4 b2 = *(const float4*)&W2s[kk][tx * 4];
            acc1[0][0]+=a.x*b1.x; acc1[0][1]+=a.x*b1.y; acc1[0][2]+=a.x*b1.z; acc1[0][3]+=a.x*b1.w;
            acc1[1][0]+=a.y*b1.x; acc1[1][1]+=a.y*b1.y; acc1[1][2]+=a.y*b1.z; acc1[1][3]+=a.y*b1.w;
            acc1[2][0]+=a.z*b1.x; acc1[2][1]+=a.z*b1.y; acc1[2][2]+=a.z*b1.z; acc1[2][3]+=a.z*b1.w;
            acc1[3][0]+=a.w*b1.x; acc1[3][1]+=a.w*b1.y; acc1[3][2]+=a.w*b1.z; acc1[3][3]+=a.w*b1.w;
            acc2[0][0]+=a.x*b2.x; acc2[0][1]+=a.x*b2.y; acc2[0][2]+=a.x*b2.z; acc2[0][3]+=a.x*b2.w;
            acc2[1][0]+=a.y*b2.x; acc2[1][1]+=a.y*b2.y; acc2[1][2]+=a.y*b2.z; acc2[1][3]+=a.y*b2.w;
            acc2[2][0]+=a.z*b2.x; acc2[2][1]+=a.z*b2.y; acc2[2][2]+=a.z*b2.z; acc2[2][3]+=a.z*b2.w;
            acc2[3][0]+=a.w*b2.x; acc2[3][1]+=a.w*b2.y; acc2[3][2]+=a.w*b2.z; acc2[3][3]+=a.w*b2.w;
        }
    }
    #pragma unroll
    for (int i = 0; i < 4; ++i) {
        const size_t r = (size_t)(bm + ty * 4 + i);
        float4 out;
        float v1, v2;
        v1 = acc1[i][0]; v2 = acc2[i][0]; out.x = (v1 / (1.0f + __expf(-v1))) * v2;
        v1 = acc1[i][1]; v2 = acc2[i][1]; out.y = (v1 / (1.0f + __expf(-v1))) * v2;
        v1 = acc1[i][2]; v2 = acc2[i][2]; out.z = (v1 / (1.0f + __expf(-v1))) * v2;
        v1 = acc1[i][3]; v2 = acc2[i][3]; out.w = (v1 / (1.0f + __expf(-v1))) * v2;
        *(float4*)(Mo + r * N + bn + tx * 4) = out;
    }
}

// ============================ RoPE (in place) ============================
__global__ __launch_bounds__(256) void rope_k(float* __restrict__ t,
        const float* __restrict__ fc, int nh)
{
    const int e = blockIdx.x * 256 + threadIdx.x;
    const int per_row = nh * 64;
    const int row = e / per_row;
    const int rem = e - row * per_row;
    const int hh = rem >> 6, i = rem & 63;
    const int tt = row & (TT - 1);
    const float c = fc[tt * HDIM + i * 2];
    const float s = fc[tt * HDIM + i * 2 + 1];
    float2* p = (float2*)(t + (size_t)row * (nh * HDIM) + hh * HDIM + i * 2);
    float2 v = *p;
    float2 o;
    o.x = v.x * c - v.y * s;
    o.y = v.x * s + v.y * c;
    *p = o;
}

// ============================ Flash attention (f32) ============================
// One block per (b, h, 64-query tile). 256 threads = (tx 0..15) x (ty 0..15).
// Thread owns q rows ty*4+i (i<4); d columns u*64 + tx*4 + c (u<2, c<4).
// K tiles of 32 keys staged in LDS (k-major), V row-major, online softmax.
#define QB 64
#define KVB 32

__global__ __launch_bounds__(256) void flash_attn(const float* __restrict__ q,
        const float* __restrict__ k, const float* __restrict__ v,
        float* __restrict__ y)
{
    __shared__ float Qs[HDIM][QB + 4];   // [k][q]  34.8 KB
    __shared__ float Ks[HDIM][KVB + 4];  // [k][j]  18.4 KB
    __shared__ float Vs[KVB][HDIM + 4];  // [j][d]  16.9 KB
    __shared__ float Ps[QB][KVB + 4];    // [q][j]   9.2 KB

    const int qt = (TT / QB - 1) - blockIdx.x;   // longest blocks first
    const int h  = blockIdx.y;
    const int b  = blockIdx.z;
    const int g  = h >> 2;                        // kv head (REP=4)
    const int qbase = qt * QB;

    const int tid = threadIdx.x;
    const int tx = tid & 15, ty = tid >> 4;

    // ---- load Q tile transposed: Qs[kk][qq] ----
    {
        const int r  = tid >> 2;            // q row 0..63
        const int kc = (tid & 3) * 32;      // k chunk
        const float* qrow = q + ((size_t)(b * TT + qbase + r) * CC) + h * HDIM + kc;
        #pragma unroll
        for (int c = 0; c < 8; ++c) {
            float4 qv = *(const float4*)(qrow + c * 4);
            const int kk = kc + c * 4;
            Qs[kk + 0][r] = qv.x; Qs[kk + 1][r] = qv.y;
            Qs[kk + 2][r] = qv.z; Qs[kk + 3][r] = qv.w;
        }
    }

    float m_r[4], l_r[4];
    float acc[4][2][4];
    #pragma unroll
    for (int i = 0; i < 4; ++i) {
        m_r[i] = -1e30f; l_r[i] = 0.0f;
        #pragma unroll
        for (int u = 0; u < 2; ++u)
            #pragma unroll
            for (int c = 0; c < 4; ++c) acc[i][u][c] = 0.0f;
    }

    const float scale = 0.08838834764831845f;  // 1/sqrt(128)
    const int ntiles = (qbase + QB) / KVB;
    const int jrow = tid & 31;                 // staging: kv row
    const int jkc  = (tid >> 5) * 16;          // staging: 16-float chunk

    for (int tile = 0; tile < ntiles; ++tile) {
        const int jbase = tile * KVB;
        __syncthreads();  // previous tile's reads done before overwrite
        // ---- stage K (transposed) and V (row-major) ----
        {
            const float* krow = k + ((size_t)(b * TT + jbase + jrow) * (NKV * HDIM)) + g * HDIM + jkc;
            const float* vrow = v + ((size_t)(b * TT + jbase + jrow) * (NKV * HDIM)) + g * HDIM + jkc;
            #pragma unroll
            for (int c = 0; c < 4; ++c) {
                float4 kv = *(const float4*)(krow + c * 4);
                const int kk = jkc + c * 4;
                Ks[kk + 0][jrow] = kv.x; Ks[kk + 1][jrow] = kv.y;
                Ks[kk + 2][jrow] = kv.z; Ks[kk + 3][jrow] = kv.w;
                float4 vv = *(const float4*)(vrow + c * 4);
                *(float4*)&Vs[jrow][jkc + c * 4] = vv;
            }
        }
        __syncthreads();

        // ---- S = Q @ K^T (4q x 2j per thread) ----
        float s[4][2] = {};
        #pragma unroll 4
        for (int kk = 0; kk < HDIM; ++kk) {
            float4 qv = *(const float4*)&Qs[kk][ty * 4];
            float2 kv = *(const float2*)&Ks[kk][tx * 2];
            s[0][0] += qv.x * kv.x; s[0][1] += qv.x * kv.y;
            s[1][0] += qv.y * kv.x; s[1][1] += qv.y * kv.y;
            s[2][0] += qv.z * kv.x; s[2][1] += qv.z * kv.y;
            s[3][0] += qv.w * kv.x; s[3][1] += qv.w * kv.y;
        }

        // ---- mask + online softmax update ----
        #pragma unroll
        for (int i = 0; i < 4; ++i) {
            const int sq = qbase + ty * 4 + i;
            float s0 = (jbase + tx * 2 + 0 <= sq) ? s[i][0] * scale : -1e30f;
            float s1 = (jbase + tx * 2 + 1 <= sq) ? s[i][1] * scale : -1e30f;
            float tmax = fmaxf(s0, s1);
            tmax = fmaxf(tmax, __shfl_xor(tmax, 1));
            tmax = fmaxf(tmax, __shfl_xor(tmax, 2));
            tmax = fmaxf(tmax, __shfl_xor(tmax, 4));
            tmax = fmaxf(tmax, __shfl_xor(tmax, 8));
            const float m_new = fmaxf(m_r[i], tmax);
            const float alpha = __expf(m_r[i] - m_new);
            const float p0 = __expf(s0 - m_new);
            const float p1 = __expf(s1 - m_new);
            float tsum = p0 + p1;
            tsum += __shfl_xor(tsum, 1);
            tsum += __shfl_xor(tsum, 2);
            tsum += __shfl_xor(tsum, 4);
            tsum += __shfl_xor(tsum, 8);
            l_r[i] = l_r[i] * alpha + tsum;
            m_r[i] = m_new;
            #pragma unroll
            for (int u = 0; u < 2; ++u)
                #pragma unroll
                for (int c = 0; c < 4; ++c) acc[i][u][c] *= alpha;
            Ps[ty * 4 + i][tx * 2 + 0] = p0;
            Ps[ty * 4 + i][tx * 2 + 1] = p1;
        }
        __syncthreads();

        // ---- O += P @ V ----
        #pragma unroll 4
        for (int j = 0; j < KVB; ++j) {
            float p0 = Ps[ty * 4 + 0][j];
            float p1 = Ps[ty * 4 + 1][j];
            float p2 = Ps[ty * 4 + 2][j];
            float p3 = Ps[ty * 4 + 3][j];
            #pragma unroll
            for (int u = 0; u < 2; ++u) {
                float4 vv = *(const float4*)&Vs[j][u * 64 + tx * 4];
                acc[0][u][0] += p0 * vv.x; acc[0][u][1] += p0 * vv.y;
                acc[0][u][2] += p0 * vv.z; acc[0][u][3] += p0 * vv.w;
                acc[1][u][0] += p1 * vv.x; acc[1][u][1] += p1 * vv.y;
                acc[1][u][2] += p1 * vv.z; acc[1][u][3] += p1 * vv.w;
                acc[2][u][0] += p2 * vv.x; acc[2][u][1] += p2 * vv.y;
                acc[2][u][2] += p2 * vv.z; acc[2][u][3] += p2 * vv.w;
                acc[3][u][0] += p3 * vv.x; acc[3][u][1] += p3 * vv.y;
                acc[3][u][2] += p3 * vv.z; acc[3][u][3] += p3 * vv.w;
            }
        }
    }

    // ---- epilogue: normalize and store ----
    #pragma unroll
    for (int i = 0; i < 4; ++i) {
        const float inv = 1.0f / l_r[i];
        float* yrow = y + ((size_t)(b * TT + qbase + ty * 4 + i) * CC) + h * HDIM;
        #pragma unroll
        for (int u = 0; u < 2; ++u) {
            float4 o;
            o.x = acc[i][u][0] * inv; o.y = acc[i][u][1] * inv;
            o.z = acc[i][u][2] * inv; o.w = acc[i][u][3] * inv;
            *(float4*)(yrow + u * 64 + tx * 4) = o;
        }
    }
}

// ============================ launch ============================
extern "C" void kernel_launch(void* const* d_in, const int* in_sizes, int n_in,
                              void* d_out, int out_size, void* d_ws, size_t ws_size,
                              hipStream_t stream)
{
    (void)in_sizes; (void)n_in; (void)out_size; (void)ws_size;
    const float* x     = (const float*)d_in[0];
    const float* fc    = (const float*)d_in[1];
    const float* wq    = (const float*)d_in[2];
    const float* wk    = (const float*)d_in[3];
    const float* wv    = (const float*)d_in[4];
    const float* wo    = (const float*)d_in[5];
    const float* w1    = (const float*)d_in[6];
    const float* w2    = (const float*)d_in[7];
    const float* cproj = (const float*)d_in[8];
    const float* g1    = (const float*)d_in[9];
    const float* g2    = (const float*)d_in[10];
    float* out = (float*)d_out;
    float* ws  = (float*)d_ws;

    const int ROWS = NB * TT;                 // 4096
    const size_t o_x2 = 0;
    const size_t o_h  = (size_t)ROWS * CC;
    const size_t o_q  = o_h + (size_t)ROWS * CC;
    const size_t o_k  = o_q + (size_t)ROWS * CC;
    const size_t o_v  = o_k + (size_t)ROWS * NKV * HDIM;
    const size_t o_y  = o_v + (size_t)ROWS * NKV * HDIM;
    const size_t o_m  = o_q;

    float* h  = ws + o_h;
    float* qb = ws + o_q;
    float* kb = ws + o_k;
    float* vb = ws + o_v;
    float* yb = ws + o_y;
    float* x2 = ws + o_x2;
    float* mb = ws + o_m;

    rmsnorm_k<<<ROWS, 256, 0, stream>>>(x, g1, h);
    gemm_nt<<<dim3(CC / BN, ROWS / BM), 256, 0, stream>>>(h, wq, nullptr, qb, ROWS, CC, CC);
    gemm_nt<<<dim3((NKV * HDIM) / BN, ROWS / BM), 256, 0, stream>>>(h, wk, nullptr, kb, ROWS, NKV * HDIM, CC);
    gemm_nt<<<dim3((NKV * HDIM) / BN, ROWS / BM), 256, 0, stream>>>(h, wv, nullptr, vb, ROWS, NKV * HDIM, CC);
    rope_k<<<(ROWS * NH * 64) / 256, 256, 0, stream>>>(qb, fc, NH);
    rope_k<<<(ROWS * NKV * 64) / 256, 256, 0, stream>>>(kb, fc, NKV);
    flash_attn<<<dim3(TT / QB, NH, NB), 256, 0, stream>>>(qb, kb, vb, yb);
    gemm_nt<<<dim3(CC / BN, ROWS / BM), 256, 0, stream>>>(yb, wo, x, x2, ROWS, CC, CC);
    rmsnorm_k<<<ROWS, 256, 0, stream>>>(x2, g2, h);
    gemm_ffn_fused<<<dim3(NFFN / BN, ROWS / BM), 256, 0, stream>>>(h, w1, w2, mb, ROWS, NFFN, CC);
    gemm_nt<<<dim3(CC / BN, ROWS / BM), 256, 0, stream>>>(mb, cproj, x2, out, ROWS, CC, NFFN);
}

// Round 5
// 1873.928 us; speedup vs baseline: 5.8353x; 3.6650x over previous
//
#include <hip/hip_runtime.h>
#include <hip/hip_bf16.h>
#include <math.h>

#define TT   2048
#define CC   2048
#define NB   2
#define NH   16
#define NKV  4
#define HDIM 128
#define NFFN 5632

typedef __attribute__((ext_vector_type(8))) short     bf8;    // MFMA A/B frag (8 bf16)
typedef __attribute__((ext_vector_type(4))) float     f32x4;  // MFMA C/D frag
typedef __attribute__((ext_vector_type(8))) unsigned short u16x8;
typedef __attribute__((ext_vector_type(4))) unsigned short u16x4;

__device__ __forceinline__ float b2f(unsigned short u) {
    union { unsigned u; float f; } v; v.u = ((unsigned)u) << 16; return v.f;
}
__device__ __forceinline__ unsigned short f2bf(float f) {
    union { float f; unsigned u; } v; v.f = f;
    unsigned r = (v.u + 0x7fffu + ((v.u >> 16) & 1u)) >> 16;
    return (unsigned short)r;
}
__device__ __forceinline__ void gll16(const void* g, void* l) {
    __builtin_amdgcn_global_load_lds((const __attribute__((address_space(1))) void*)g,
                                     (__attribute__((address_space(3))) void*)l, 16, 0, 0);
}

// ============================ f32 -> bf16 convert ============================
__global__ __launch_bounds__(256) void cvt_k(const float* __restrict__ in,
        __hip_bfloat16* __restrict__ out)
{
    const size_t i = ((size_t)blockIdx.x * 256 + threadIdx.x) * 8;
    float4 a = *(const float4*)(in + i);
    float4 b = *(const float4*)(in + i + 4);
    u16x8 v;
    v[0] = f2bf(a.x); v[1] = f2bf(a.y); v[2] = f2bf(a.z); v[3] = f2bf(a.w);
    v[4] = f2bf(b.x); v[5] = f2bf(b.y); v[6] = f2bf(b.z); v[7] = f2bf(b.w);
    *(u16x8*)((unsigned short*)out + i) = v;
}

// ============================ RMSNorm ============================
__global__ __launch_bounds__(256) void rms_f32_k(const float* __restrict__ x,
        const float* __restrict__ g, __hip_bfloat16* __restrict__ o)
{
    const size_t row = blockIdx.x;
    const int e0 = threadIdx.x * 8;
    float4 a = *(const float4*)(x + row * CC + e0);
    float4 b = *(const float4*)(x + row * CC + e0 + 4);
    float vals[8] = {a.x, a.y, a.z, a.w, b.x, b.y, b.z, b.w};
    float s = 0.f;
    #pragma unroll
    for (int e = 0; e < 8; ++e) s += vals[e] * vals[e];
    #pragma unroll
    for (int off = 32; off; off >>= 1) s += __shfl_xor(s, off);
    __shared__ float wsum[4];
    if ((threadIdx.x & 63) == 0) wsum[threadIdx.x >> 6] = s;
    __syncthreads();
    float scale = rsqrtf((wsum[0] + wsum[1] + wsum[2] + wsum[3]) * (1.0f / CC) + 1e-5f);
    float4 g0 = *(const float4*)(g + e0);
    float4 g1 = *(const float4*)(g + e0 + 4);
    float gs[8] = {g0.x, g0.y, g0.z, g0.w, g1.x, g1.y, g1.z, g1.w};
    u16x8 ov;
    #pragma unroll
    for (int e = 0; e < 8; ++e) ov[e] = f2bf(vals[e] * scale * gs[e]);
    *(u16x8*)((unsigned short*)o + row * CC + e0) = ov;
}

__global__ __launch_bounds__(256) void rms_bf16_k(const __hip_bfloat16* __restrict__ x,
        const float* __restrict__ g, __hip_bfloat16* __restrict__ o)
{
    const size_t row = blockIdx.x;
    const int e0 = threadIdx.x * 8;
    u16x8 xv = *(const u16x8*)((const unsigned short*)x + row * CC + e0);
    float vals[8];
    #pragma unroll
    for (int e = 0; e < 8; ++e) vals[e] = b2f(xv[e]);
    float s = 0.f;
    #pragma unroll
    for (int e = 0; e < 8; ++e) s += vals[e] * vals[e];
    #pragma unroll
    for (int off = 32; off; off >>= 1) s += __shfl_xor(s, off);
    __shared__ float wsum[4];
    if ((threadIdx.x & 63) == 0) wsum[threadIdx.x >> 6] = s;
    __syncthreads();
    float scale = rsqrtf((wsum[0] + wsum[1] + wsum[2] + wsum[3]) * (1.0f / CC) + 1e-5f);
    float4 g0 = *(const float4*)(g + e0);
    float4 g1 = *(const float4*)(g + e0 + 4);
    float gs[8] = {g0.x, g0.y, g0.z, g0.w, g1.x, g1.y, g1.z, g1.w};
    u16x8 ov;
    #pragma unroll
    for (int e = 0; e < 8; ++e) ov[e] = f2bf(vals[e] * scale * gs[e]);
    *(u16x8*)((unsigned short*)o + row * CC + e0) = ov;
}

// ============================ RoPE (bf16 in place) ============================
__global__ __launch_bounds__(256) void rope_k(__hip_bfloat16* __restrict__ t,
        const float* __restrict__ fc, int nh)
{
    const int e = blockIdx.x * 256 + threadIdx.x;
    const int per_row = nh * 64;
    const int row = e / per_row;
    const int rem = e - row * per_row;
    const int hh = rem >> 6, i = rem & 63;
    const int tt = row & (TT - 1);
    const float c = fc[tt * HDIM + i * 2];
    const float s = fc[tt * HDIM + i * 2 + 1];
    unsigned short* p = (unsigned short*)t + (size_t)row * (nh * HDIM) + hh * HDIM + i * 2;
    float a = b2f(p[0]), b = b2f(p[1]);
    p[0] = f2bf(a * c - b * s);
    p[1] = f2bf(a * s + b * c);
}

// ============================ bf16 MFMA GEMM (NT) ============================
// C[M,N] = A[M,K] @ W[N,K]^T (+ res). 128x128 tile, BK=32, 4 waves, 4x4 16x16 frags.
#define GBM 128
#define GBN 128
#define GBK 32

template<int RES, int OUTB>
__global__ __launch_bounds__(256) void gemm_mfma(
        const __hip_bfloat16* __restrict__ A,
        const __hip_bfloat16* __restrict__ W,
        const void* __restrict__ Rp,
        void* __restrict__ Cp,
        int M, int N, int K)
{
    __shared__ alignas(16) __hip_bfloat16 As[GBM][GBK];
    __shared__ alignas(16) __hip_bfloat16 Ws[GBN][GBK];
    const int tid  = threadIdx.x;
    const int lane = tid & 63;
    const int wid  = tid >> 6;
    const int wr = wid >> 1, wc = wid & 1;
    const int bm = blockIdx.y * GBM, bn = blockIdx.x * GBN;
    const int l4  = lane >> 2;
    const int lk8 = (lane & 3) * 8;
    const int fr  = lane & 15;
    const int fk  = (lane >> 4) * 8;

    f32x4 acc[4][4];
    #pragma unroll
    for (int m = 0; m < 4; ++m)
        #pragma unroll
        for (int n = 0; n < 4; ++n) acc[m][n] = (f32x4){0.f, 0.f, 0.f, 0.f};

    const __hip_bfloat16* ga0 = A + (size_t)(bm + wid * 32 + l4) * K + lk8;
    const __hip_bfloat16* ga1 = A + (size_t)(bm + wid * 32 + 16 + l4) * K + lk8;
    const __hip_bfloat16* gw0 = W + (size_t)(bn + wid * 32 + l4) * K + lk8;
    const __hip_bfloat16* gw1 = W + (size_t)(bn + wid * 32 + 16 + l4) * K + lk8;
    void* la0 = &As[wid * 32][0];
    void* la1 = &As[wid * 32 + 16][0];
    void* lw0 = &Ws[wid * 32][0];
    void* lw1 = &Ws[wid * 32 + 16][0];

    for (int k0 = 0; k0 < K; k0 += GBK) {
        __syncthreads();
        gll16(ga0 + k0, la0);
        gll16(ga1 + k0, la1);
        gll16(gw0 + k0, lw0);
        gll16(gw1 + k0, lw1);
        __syncthreads();
        bf8 af[4];
        #pragma unroll
        for (int m = 0; m < 4; ++m)
            af[m] = *(const bf8*)&As[wr * 64 + m * 16 + fr][fk];
        #pragma unroll
        for (int n = 0; n < 4; ++n) {
            bf8 wf = *(const bf8*)&Ws[wc * 64 + n * 16 + fr][fk];
            #pragma unroll
            for (int m = 0; m < 4; ++m)
                acc[m][n] = __builtin_amdgcn_mfma_f32_16x16x32_bf16(af[m], wf, acc[m][n], 0, 0, 0);
        }
    }

    const int rj = (lane >> 4) * 4;
    #pragma unroll
    for (int m = 0; m < 4; ++m) {
        #pragma unroll
        for (int j = 0; j < 4; ++j) {
            const size_t row = (size_t)(bm + wr * 64 + m * 16 + rj + j);
            #pragma unroll
            for (int n = 0; n < 4; ++n) {
                const size_t col = (size_t)(bn + wc * 64 + n * 16 + fr);
                float v = acc[m][n][j];
                if (RES == 1) v += ((const float*)Rp)[row * N + col];
                if (RES == 2) v += b2f(((const unsigned short*)Rp)[row * N + col]);
                if (OUTB) ((unsigned short*)Cp)[row * N + col] = f2bf(v);
                else      ((float*)Cp)[row * N + col] = v;
            }
        }
    }
}

// ============================ dual-B FFN MFMA GEMM ============================
__global__ __launch_bounds__(256) void gemm_ffn_mfma(
        const __hip_bfloat16* __restrict__ A,
        const __hip_bfloat16* __restrict__ W1,
        const __hip_bfloat16* __restrict__ W2,
        __hip_bfloat16* __restrict__ Mo,
        int M, int N, int K)
{
    __shared__ alignas(16) __hip_bfloat16 As [GBM][GBK];
    __shared__ alignas(16) __hip_bfloat16 W1s[GBN][GBK];
    __shared__ alignas(16) __hip_bfloat16 W2s[GBN][GBK];
    const int tid  = threadIdx.x;
    const int lane = tid & 63;
    const int wid  = tid >> 6;
    const int wr = wid >> 1, wc = wid & 1;
    const int bm = blockIdx.y * GBM, bn = blockIdx.x * GBN;
    const int l4  = lane >> 2;
    const int lk8 = (lane & 3) * 8;
    const int fr  = lane & 15;
    const int fk  = (lane >> 4) * 8;

    f32x4 acc1[4][4], acc2[4][4];
    #pragma unroll
    for (int m = 0; m < 4; ++m)
        #pragma unroll
        for (int n = 0; n < 4; ++n) {
            acc1[m][n] = (f32x4){0.f, 0.f, 0.f, 0.f};
            acc2[m][n] = (f32x4){0.f, 0.f, 0.f, 0.f};
        }

    const __hip_bfloat16* ga0 = A  + (size_t)(bm + wid * 32 + l4) * K + lk8;
    const __hip_bfloat16* ga1 = A  + (size_t)(bm + wid * 32 + 16 + l4) * K + lk8;
    const __hip_bfloat16* g10 = W1 + (size_t)(bn + wid * 32 + l4) * K + lk8;
    const __hip_bfloat16* g11 = W1 + (size_t)(bn + wid * 32 + 16 + l4) * K + lk8;
    const __hip_bfloat16* g20 = W2 + (size_t)(bn + wid * 32 + l4) * K + lk8;
    const __hip_bfloat16* g21 = W2 + (size_t)(bn + wid * 32 + 16 + l4) * K + lk8;
    void* la0 = &As [wid * 32][0];
    void* la1 = &As [wid * 32 + 16][0];
    void* l10 = &W1s[wid * 32][0];
    void* l11 = &W1s[wid * 32 + 16][0];
    void* l20 = &W2s[wid * 32][0];
    void* l21 = &W2s[wid * 32 + 16][0];

    for (int k0 = 0; k0 < K; k0 += GBK) {
        __syncthreads();
        gll16(ga0 + k0, la0);
        gll16(ga1 + k0, la1);
        gll16(g10 + k0, l10);
        gll16(g11 + k0, l11);
        gll16(g20 + k0, l20);
        gll16(g21 + k0, l21);
        __syncthreads();
        bf8 af[4];
        #pragma unroll
        for (int m = 0; m < 4; ++m)
            af[m] = *(const bf8*)&As[wr * 64 + m * 16 + fr][fk];
        #pragma unroll
        for (int n = 0; n < 4; ++n) {
            bf8 w1f = *(const bf8*)&W1s[wc * 64 + n * 16 + fr][fk];
            bf8 w2f = *(const bf8*)&W2s[wc * 64 + n * 16 + fr][fk];
            #pragma unroll
            for (int m = 0; m < 4; ++m) {
                acc1[m][n] = __builtin_amdgcn_mfma_f32_16x16x32_bf16(af[m], w1f, acc1[m][n], 0, 0, 0);
                acc2[m][n] = __builtin_amdgcn_mfma_f32_16x16x32_bf16(af[m], w2f, acc2[m][n], 0, 0, 0);
            }
        }
    }

    const int rj = (lane >> 4) * 4;
    #pragma unroll
    for (int m = 0; m < 4; ++m) {
        #pragma unroll
        for (int j = 0; j < 4; ++j) {
            const size_t row = (size_t)(bm + wr * 64 + m * 16 + rj + j);
            #pragma unroll
            for (int n = 0; n < 4; ++n) {
                const size_t col = (size_t)(bn + wc * 64 + n * 16 + fr);
                float a1 = acc1[m][n][j];
                float a2 = acc2[m][n][j];
                float sv = (a1 / (1.0f + __expf(-a1))) * a2;
                ((unsigned short*)Mo)[row * N + col] = f2bf(sv);
            }
        }
    }
}

// ============================ Flash attention (bf16 io, f32 math) ============================
#define QB 64
#define KVB 32

__global__ __launch_bounds__(256) void flash_attn(const __hip_bfloat16* __restrict__ q,
        const __hip_bfloat16* __restrict__ k, const __hip_bfloat16* __restrict__ v,
        __hip_bfloat16* __restrict__ y)
{
    __shared__ float Qs[HDIM][QB + 4];
    __shared__ float Ks[HDIM][KVB + 4];
    __shared__ float Vs[KVB][HDIM + 4];
    __shared__ float Ps[QB][KVB + 4];

    const int qt = (TT / QB - 1) - blockIdx.x;
    const int h  = blockIdx.y;
    const int b  = blockIdx.z;
    const int g  = h >> 2;
    const int qbase = qt * QB;

    const int tid = threadIdx.x;
    const int tx = tid & 15, ty = tid >> 4;

    {
        const int r  = tid >> 2;
        const int kc = (tid & 3) * 32;
        const unsigned short* qrow = (const unsigned short*)q + ((size_t)(b * TT + qbase + r) * CC) + h * HDIM + kc;
        #pragma unroll
        for (int c = 0; c < 4; ++c) {
            u16x8 qv = *(const u16x8*)(qrow + c * 8);
            #pragma unroll
            for (int e = 0; e < 8; ++e) Qs[kc + c * 8 + e][r] = b2f(qv[e]);
        }
    }

    float m_r[4], l_r[4];
    float acc[4][2][4];
    #pragma unroll
    for (int i = 0; i < 4; ++i) {
        m_r[i] = -1e30f; l_r[i] = 0.0f;
        #pragma unroll
        for (int u = 0; u < 2; ++u)
            #pragma unroll
            for (int c = 0; c < 4; ++c) acc[i][u][c] = 0.0f;
    }

    const float scale = 0.08838834764831845f;
    const int ntiles = (qbase + QB) / KVB;
    const int jrow = tid & 31;
    const int jkc  = (tid >> 5) * 16;

    for (int tile = 0; tile < ntiles; ++tile) {
        const int jbase = tile * KVB;
        __syncthreads();
        {
            const unsigned short* krow = (const unsigned short*)k + ((size_t)(b * TT + jbase + jrow) * (NKV * HDIM)) + g * HDIM + jkc;
            const unsigned short* vrow = (const unsigned short*)v + ((size_t)(b * TT + jbase + jrow) * (NKV * HDIM)) + g * HDIM + jkc;
            #pragma unroll
            for (int c = 0; c < 2; ++c) {
                u16x8 kv = *(const u16x8*)(krow + c * 8);
                u16x8 vv = *(const u16x8*)(vrow + c * 8);
                #pragma unroll
                for (int e = 0; e < 8; ++e) {
                    Ks[jkc + c * 8 + e][jrow] = b2f(kv[e]);
                    Vs[jrow][jkc + c * 8 + e] = b2f(vv[e]);
                }
            }
        }
        __syncthreads();

        float s[4][2] = {};
        #pragma unroll 4
        for (int kk = 0; kk < HDIM; ++kk) {
            float4 qv = *(const float4*)&Qs[kk][ty * 4];
            float2 kv = *(const float2*)&Ks[kk][tx * 2];
            s[0][0] += qv.x * kv.x; s[0][1] += qv.x * kv.y;
            s[1][0] += qv.y * kv.x; s[1][1] += qv.y * kv.y;
            s[2][0] += qv.z * kv.x; s[2][1] += qv.z * kv.y;
            s[3][0] += qv.w * kv.x; s[3][1] += qv.w * kv.y;
        }

        #pragma unroll
        for (int i = 0; i < 4; ++i) {
            const int sq = qbase + ty * 4 + i;
            float s0 = (jbase + tx * 2 + 0 <= sq) ? s[i][0] * scale : -1e30f;
            float s1 = (jbase + tx * 2 + 1 <= sq) ? s[i][1] * scale : -1e30f;
            float tmax = fmaxf(s0, s1);
            tmax = fmaxf(tmax, __shfl_xor(tmax, 1));
            tmax = fmaxf(tmax, __shfl_xor(tmax, 2));
            tmax = fmaxf(tmax, __shfl_xor(tmax, 4));
            tmax = fmaxf(tmax, __shfl_xor(tmax, 8));
            const float m_new = fmaxf(m_r[i], tmax);
            const float alpha = __expf(m_r[i] - m_new);
            const float p0 = __expf(s0 - m_new);
            const float p1 = __expf(s1 - m_new);
            float tsum = p0 + p1;
            tsum += __shfl_xor(tsum, 1);
            tsum += __shfl_xor(tsum, 2);
            tsum += __shfl_xor(tsum, 4);
            tsum += __shfl_xor(tsum, 8);
            l_r[i] = l_r[i] * alpha + tsum;
            m_r[i] = m_new;
            #pragma unroll
            for (int u = 0; u < 2; ++u)
                #pragma unroll
                for (int c = 0; c < 4; ++c) acc[i][u][c] *= alpha;
            Ps[ty * 4 + i][tx * 2 + 0] = p0;
            Ps[ty * 4 + i][tx * 2 + 1] = p1;
        }
        __syncthreads();

        #pragma unroll 4
        for (int j = 0; j < KVB; ++j) {
            float p0 = Ps[ty * 4 + 0][j];
            float p1 = Ps[ty * 4 + 1][j];
            float p2 = Ps[ty * 4 + 2][j];
            float p3 = Ps[ty * 4 + 3][j];
            #pragma unroll
            for (int u = 0; u < 2; ++u) {
                float4 vv = *(const float4*)&Vs[j][u * 64 + tx * 4];
                acc[0][u][0] += p0 * vv.x; acc[0][u][1] += p0 * vv.y;
                acc[0][u][2] += p0 * vv.z; acc[0][u][3] += p0 * vv.w;
                acc[1][u][0] += p1 * vv.x; acc[1][u][1] += p1 * vv.y;
                acc[1][u][2] += p1 * vv.z; acc[1][u][3] += p1 * vv.w;
                acc[2][u][0] += p2 * vv.x; acc[2][u][1] += p2 * vv.y;
                acc[2][u][2] += p2 * vv.z; acc[2][u][3] += p2 * vv.w;
                acc[3][u][0] += p3 * vv.x; acc[3][u][1] += p3 * vv.y;
                acc[3][u][2] += p3 * vv.z; acc[3][u][3] += p3 * vv.w;
            }
        }
    }

    #pragma unroll
    for (int i = 0; i < 4; ++i) {
        const float inv = 1.0f / l_r[i];
        unsigned short* yrow = (unsigned short*)y + ((size_t)(b * TT + qbase + ty * 4 + i) * CC) + h * HDIM;
        #pragma unroll
        for (int u = 0; u < 2; ++u) {
            u16x4 o;
            o[0] = f2bf(acc[i][u][0] * inv); o[1] = f2bf(acc[i][u][1] * inv);
            o[2] = f2bf(acc[i][u][2] * inv); o[3] = f2bf(acc[i][u][3] * inv);
            *(u16x4*)(yrow + u * 64 + tx * 4) = o;
        }
    }
}

// ============================ launch ============================
extern "C" void kernel_launch(void* const* d_in, const int* in_sizes, int n_in,
                              void* d_out, int out_size, void* d_ws, size_t ws_size,
                              hipStream_t stream)
{
    (void)in_sizes; (void)n_in; (void)out_size; (void)ws_size;
    const float* x     = (const float*)d_in[0];
    const float* fc    = (const float*)d_in[1];
    const float* wq    = (const float*)d_in[2];
    const float* wk    = (const float*)d_in[3];
    const float* wv    = (const float*)d_in[4];
    const float* wo    = (const float*)d_in[5];
    const float* w1    = (const float*)d_in[6];
    const float* w2    = (const float*)d_in[7];
    const float* cproj = (const float*)d_in[8];
    const float* g1    = (const float*)d_in[9];
    const float* g2    = (const float*)d_in[10];
    float* out = (float*)d_out;

    const int ROWS = NB * TT;  // 4096
    unsigned char* wsb = (unsigned char*)d_ws;
    // layout (bytes): [0,16M) x2_bf | [16M,32M) h_bf | [32M, 32M+44M) S1 | [76M, 120M) S2
    __hip_bfloat16* x2b = (__hip_bfloat16*)(wsb);
    __hip_bfloat16* hb  = (__hip_bfloat16*)(wsb + (16u << 20));
    unsigned char* S1 = wsb + (32u << 20);
    unsigned char* S2 = wsb + (32u << 20) + 46137344u;
    // phase A views of S1: qb 16MB | kb 4MB @16M | vb 4MB @20M | yb 16MB @24M (ends 40M < 44M)
    __hip_bfloat16* qb = (__hip_bfloat16*)(S1);
    __hip_bfloat16* kb = (__hip_bfloat16*)(S1 + (16u << 20));
    __hip_bfloat16* vb = (__hip_bfloat16*)(S1 + (20u << 20));
    __hip_bfloat16* yb = (__hip_bfloat16*)(S1 + (24u << 20));
    // phase B views of S1
    __hip_bfloat16* w1b = (__hip_bfloat16*)(S1);
    __hip_bfloat16* w2b = (__hip_bfloat16*)(S1 + 23068672u);
    __hip_bfloat16* cpb = (__hip_bfloat16*)(S1);
    // S2: phase A = weight scratch (qkv/wo), phase B = FFN activation
    __hip_bfloat16* wbuf = (__hip_bfloat16*)(S2);
    __hip_bfloat16* mbb  = (__hip_bfloat16*)(S2);

    // 1. h = rmsnorm(x)*g1  (bf16)
    rms_f32_k<<<ROWS, 256, 0, stream>>>(x, g1, hb);
    // 2. q/k/v projections (bf16 MFMA)
    cvt_k<<<(CC * CC) / 2048, 256, 0, stream>>>(wq, wbuf);
    gemm_mfma<0, 1><<<dim3(CC / GBN, ROWS / GBM), 256, 0, stream>>>(hb, wbuf, nullptr, qb, ROWS, CC, CC);
    cvt_k<<<(NKV * HDIM * CC) / 2048, 256, 0, stream>>>(wk, wbuf);
    gemm_mfma<0, 1><<<dim3((NKV * HDIM) / GBN, ROWS / GBM), 256, 0, stream>>>(hb, wbuf, nullptr, kb, ROWS, NKV * HDIM, CC);
    cvt_k<<<(NKV * HDIM * CC) / 2048, 256, 0, stream>>>(wv, wbuf);
    gemm_mfma<0, 1><<<dim3((NKV * HDIM) / GBN, ROWS / GBM), 256, 0, stream>>>(hb, wbuf, nullptr, vb, ROWS, NKV * HDIM, CC);
    // 3. RoPE
    rope_k<<<(ROWS * NH * 64) / 256, 256, 0, stream>>>(qb, fc, NH);
    rope_k<<<(ROWS * NKV * 64) / 256, 256, 0, stream>>>(kb, fc, NKV);
    // 4. attention
    flash_attn<<<dim3(TT / QB, NH, NB), 256, 0, stream>>>(qb, kb, vb, yb);
    // 5. x2 = bf16(x + y @ wo^T)
    cvt_k<<<(CC * CC) / 2048, 256, 0, stream>>>(wo, wbuf);
    gemm_mfma<1, 1><<<dim3(CC / GBN, ROWS / GBM), 256, 0, stream>>>(yb, wbuf, x, x2b, ROWS, CC, CC);
    // 6. h2 = rmsnorm(x2)*g2
    rms_bf16_k<<<ROWS, 256, 0, stream>>>(x2b, g2, hb);
    // 7. m = bf16(silu(h2@w1^T) * (h2@w2^T))
    cvt_k<<<(NFFN * CC) / 2048, 256, 0, stream>>>(w1, w1b);
    cvt_k<<<(NFFN * CC) / 2048, 256, 0, stream>>>(w2, w2b);
    gemm_ffn_mfma<<<dim3(NFFN / GBN, ROWS / GBM), 256, 0, stream>>>(hb, w1b, w2b, mbb, ROWS, NFFN, CC);
    // 8. out = x2 + m @ cproj^T  (f32)
    cvt_k<<<(CC * NFFN) / 2048, 256, 0, stream>>>(cproj, cpb);
    gemm_mfma<2, 0><<<dim3(CC / GBN, ROWS / GBM), 256, 0, stream>>>(mbb, cpb, x2b, out, ROWS, CC, NFFN);
}

// Round 6
// 1052.005 us; speedup vs baseline: 10.3944x; 1.7813x over previous
//
#include <hip/hip_runtime.h>
#include <hip/hip_bf16.h>
#include <math.h>

#define TT   2048
#define CC   2048
#define NB   2
#define NH   16
#define NKV  4
#define HDIM 128
#define NFFN 5632

typedef __attribute__((ext_vector_type(8))) short     bf8;    // MFMA A/B frag (8 bf16)
typedef __attribute__((ext_vector_type(4))) float     f32x4;  // MFMA C/D frag
typedef __attribute__((ext_vector_type(8))) unsigned short u16x8;
typedef __attribute__((ext_vector_type(4))) unsigned short u16x4;

__device__ __forceinline__ float b2f(unsigned short u) {
    union { unsigned u; float f; } v; v.u = ((unsigned)u) << 16; return v.f;
}
__device__ __forceinline__ unsigned short f2bf(float f) {
    union { float f; unsigned u; } v; v.f = f;
    unsigned r = (v.u + 0x7fffu + ((v.u >> 16) & 1u)) >> 16;
    return (unsigned short)r;
}
__device__ __forceinline__ void gll16(const void* g, void* l) {
    __builtin_amdgcn_global_load_lds((const __attribute__((address_space(1))) void*)g,
                                     (__attribute__((address_space(3))) void*)l, 16, 0, 0);
}

// ============================ f32 -> bf16 convert ============================
__global__ __launch_bounds__(256) void cvt_k(const float* __restrict__ in,
        __hip_bfloat16* __restrict__ out)
{
    const size_t i = ((size_t)blockIdx.x * 256 + threadIdx.x) * 8;
    float4 a = *(const float4*)(in + i);
    float4 b = *(const float4*)(in + i + 4);
    u16x8 v;
    v[0] = f2bf(a.x); v[1] = f2bf(a.y); v[2] = f2bf(a.z); v[3] = f2bf(a.w);
    v[4] = f2bf(b.x); v[5] = f2bf(b.y); v[6] = f2bf(b.z); v[7] = f2bf(b.w);
    *(u16x8*)((unsigned short*)out + i) = v;
}

// ============================ RMSNorm ============================
__global__ __launch_bounds__(256) void rms_f32_k(const float* __restrict__ x,
        const float* __restrict__ g, __hip_bfloat16* __restrict__ o)
{
    const size_t row = blockIdx.x;
    const int e0 = threadIdx.x * 8;
    float4 a = *(const float4*)(x + row * CC + e0);
    float4 b = *(const float4*)(x + row * CC + e0 + 4);
    float vals[8] = {a.x, a.y, a.z, a.w, b.x, b.y, b.z, b.w};
    float s = 0.f;
    #pragma unroll
    for (int e = 0; e < 8; ++e) s += vals[e] * vals[e];
    #pragma unroll
    for (int off = 32; off; off >>= 1) s += __shfl_xor(s, off);
    __shared__ float wsum[4];
    if ((threadIdx.x & 63) == 0) wsum[threadIdx.x >> 6] = s;
    __syncthreads();
    float scale = rsqrtf((wsum[0] + wsum[1] + wsum[2] + wsum[3]) * (1.0f / CC) + 1e-5f);
    float4 g0 = *(const float4*)(g + e0);
    float4 g1 = *(const float4*)(g + e0 + 4);
    float gs[8] = {g0.x, g0.y, g0.z, g0.w, g1.x, g1.y, g1.z, g1.w};
    u16x8 ov;
    #pragma unroll
    for (int e = 0; e < 8; ++e) ov[e] = f2bf(vals[e] * scale * gs[e]);
    *(u16x8*)((unsigned short*)o + row * CC + e0) = ov;
}

__global__ __launch_bounds__(256) void rms_bf16_k(const __hip_bfloat16* __restrict__ x,
        const float* __restrict__ g, __hip_bfloat16* __restrict__ o)
{
    const size_t row = blockIdx.x;
    const int e0 = threadIdx.x * 8;
    u16x8 xv = *(const u16x8*)((const unsigned short*)x + row * CC + e0);
    float vals[8];
    #pragma unroll
    for (int e = 0; e < 8; ++e) vals[e] = b2f(xv[e]);
    float s = 0.f;
    #pragma unroll
    for (int e = 0; e < 8; ++e) s += vals[e] * vals[e];
    #pragma unroll
    for (int off = 32; off; off >>= 1) s += __shfl_xor(s, off);
    __shared__ float wsum[4];
    if ((threadIdx.x & 63) == 0) wsum[threadIdx.x >> 6] = s;
    __syncthreads();
    float scale = rsqrtf((wsum[0] + wsum[1] + wsum[2] + wsum[3]) * (1.0f / CC) + 1e-5f);
    float4 g0 = *(const float4*)(g + e0);
    float4 g1 = *(const float4*)(g + e0 + 4);
    float gs[8] = {g0.x, g0.y, g0.z, g0.w, g1.x, g1.y, g1.z, g1.w};
    u16x8 ov;
    #pragma unroll
    for (int e = 0; e < 8; ++e) ov[e] = f2bf(vals[e] * scale * gs[e]);
    *(u16x8*)((unsigned short*)o + row * CC + e0) = ov;
}

// ============================ RoPE (bf16 in place) ============================
__global__ __launch_bounds__(256) void rope_k(__hip_bfloat16* __restrict__ t,
        const float* __restrict__ fc, int nh)
{
    const int e = blockIdx.x * 256 + threadIdx.x;
    const int per_row = nh * 64;
    const int row = e / per_row;
    const int rem = e - row * per_row;
    const int hh = rem >> 6, i = rem & 63;
    const int tt = row & (TT - 1);
    const float c = fc[tt * HDIM + i * 2];
    const float s = fc[tt * HDIM + i * 2 + 1];
    unsigned short* p = (unsigned short*)t + (size_t)row * (nh * HDIM) + hh * HDIM + i * 2;
    float a = b2f(p[0]), b = b2f(p[1]);
    p[0] = f2bf(a * c - b * s);
    p[1] = f2bf(a * s + b * c);
}

// ============================ bf16 MFMA GEMM (NT) ============================
#define GBM 128
#define GBN 128
#define GBK 32

template<int RES, int OUTB>
__global__ __launch_bounds__(256) void gemm_mfma(
        const __hip_bfloat16* __restrict__ A,
        const __hip_bfloat16* __restrict__ W,
        const void* __restrict__ Rp,
        void* __restrict__ Cp,
        int M, int N, int K)
{
    __shared__ alignas(16) __hip_bfloat16 As[GBM][GBK];
    __shared__ alignas(16) __hip_bfloat16 Ws[GBN][GBK];
    const int tid  = threadIdx.x;
    const int lane = tid & 63;
    const int wid  = tid >> 6;
    const int wr = wid >> 1, wc = wid & 1;
    const int bm = blockIdx.y * GBM, bn = blockIdx.x * GBN;
    const int l4  = lane >> 2;
    const int lk8 = (lane & 3) * 8;
    const int fr  = lane & 15;
    const int fk  = (lane >> 4) * 8;

    f32x4 acc[4][4];
    #pragma unroll
    for (int m = 0; m < 4; ++m)
        #pragma unroll
        for (int n = 0; n < 4; ++n) acc[m][n] = (f32x4){0.f, 0.f, 0.f, 0.f};

    const __hip_bfloat16* ga0 = A + (size_t)(bm + wid * 32 + l4) * K + lk8;
    const __hip_bfloat16* ga1 = A + (size_t)(bm + wid * 32 + 16 + l4) * K + lk8;
    const __hip_bfloat16* gw0 = W + (size_t)(bn + wid * 32 + l4) * K + lk8;
    const __hip_bfloat16* gw1 = W + (size_t)(bn + wid * 32 + 16 + l4) * K + lk8;
    void* la0 = &As[wid * 32][0];
    void* la1 = &As[wid * 32 + 16][0];
    void* lw0 = &Ws[wid * 32][0];
    void* lw1 = &Ws[wid * 32 + 16][0];

    for (int k0 = 0; k0 < K; k0 += GBK) {
        __syncthreads();
        gll16(ga0 + k0, la0);
        gll16(ga1 + k0, la1);
        gll16(gw0 + k0, lw0);
        gll16(gw1 + k0, lw1);
        __syncthreads();
        bf8 af[4];
        #pragma unroll
        for (int m = 0; m < 4; ++m)
            af[m] = *(const bf8*)&As[wr * 64 + m * 16 + fr][fk];
        #pragma unroll
        for (int n = 0; n < 4; ++n) {
            bf8 wf = *(const bf8*)&Ws[wc * 64 + n * 16 + fr][fk];
            #pragma unroll
            for (int m = 0; m < 4; ++m)
                acc[m][n] = __builtin_amdgcn_mfma_f32_16x16x32_bf16(af[m], wf, acc[m][n], 0, 0, 0);
        }
    }

    const int rj = (lane >> 4) * 4;
    #pragma unroll
    for (int m = 0; m < 4; ++m) {
        #pragma unroll
        for (int j = 0; j < 4; ++j) {
            const size_t row = (size_t)(bm + wr * 64 + m * 16 + rj + j);
            #pragma unroll
            for (int n = 0; n < 4; ++n) {
                const size_t col = (size_t)(bn + wc * 64 + n * 16 + fr);
                float v = acc[m][n][j];
                if (RES == 1) v += ((const float*)Rp)[row * N + col];
                if (RES == 2) v += b2f(((const unsigned short*)Rp)[row * N + col]);
                if (OUTB) ((unsigned short*)Cp)[row * N + col] = f2bf(v);
                else      ((float*)Cp)[row * N + col] = v;
            }
        }
    }
}

// ============================ dual-B FFN MFMA GEMM ============================
__global__ __launch_bounds__(256) void gemm_ffn_mfma(
        const __hip_bfloat16* __restrict__ A,
        const __hip_bfloat16* __restrict__ W1,
        const __hip_bfloat16* __restrict__ W2,
        __hip_bfloat16* __restrict__ Mo,
        int M, int N, int K)
{
    __shared__ alignas(16) __hip_bfloat16 As [GBM][GBK];
    __shared__ alignas(16) __hip_bfloat16 W1s[GBN][GBK];
    __shared__ alignas(16) __hip_bfloat16 W2s[GBN][GBK];
    const int tid  = threadIdx.x;
    const int lane = tid & 63;
    const int wid  = tid >> 6;
    const int wr = wid >> 1, wc = wid & 1;
    const int bm = blockIdx.y * GBM, bn = blockIdx.x * GBN;
    const int l4  = lane >> 2;
    const int lk8 = (lane & 3) * 8;
    const int fr  = lane & 15;
    const int fk  = (lane >> 4) * 8;

    f32x4 acc1[4][4], acc2[4][4];
    #pragma unroll
    for (int m = 0; m < 4; ++m)
        #pragma unroll
        for (int n = 0; n < 4; ++n) {
            acc1[m][n] = (f32x4){0.f, 0.f, 0.f, 0.f};
            acc2[m][n] = (f32x4){0.f, 0.f, 0.f, 0.f};
        }

    const __hip_bfloat16* ga0 = A  + (size_t)(bm + wid * 32 + l4) * K + lk8;
    const __hip_bfloat16* ga1 = A  + (size_t)(bm + wid * 32 + 16 + l4) * K + lk8;
    const __hip_bfloat16* g10 = W1 + (size_t)(bn + wid * 32 + l4) * K + lk8;
    const __hip_bfloat16* g11 = W1 + (size_t)(bn + wid * 32 + 16 + l4) * K + lk8;
    const __hip_bfloat16* g20 = W2 + (size_t)(bn + wid * 32 + l4) * K + lk8;
    const __hip_bfloat16* g21 = W2 + (size_t)(bn + wid * 32 + 16 + l4) * K + lk8;
    void* la0 = &As [wid * 32][0];
    void* la1 = &As [wid * 32 + 16][0];
    void* l10 = &W1s[wid * 32][0];
    void* l11 = &W1s[wid * 32 + 16][0];
    void* l20 = &W2s[wid * 32][0];
    void* l21 = &W2s[wid * 32 + 16][0];

    for (int k0 = 0; k0 < K; k0 += GBK) {
        __syncthreads();
        gll16(ga0 + k0, la0);
        gll16(ga1 + k0, la1);
        gll16(g10 + k0, l10);
        gll16(g11 + k0, l11);
        gll16(g20 + k0, l20);
        gll16(g21 + k0, l21);
        __syncthreads();
        bf8 af[4];
        #pragma unroll
        for (int m = 0; m < 4; ++m)
            af[m] = *(const bf8*)&As[wr * 64 + m * 16 + fr][fk];
        #pragma unroll
        for (int n = 0; n < 4; ++n) {
            bf8 w1f = *(const bf8*)&W1s[wc * 64 + n * 16 + fr][fk];
            bf8 w2f = *(const bf8*)&W2s[wc * 64 + n * 16 + fr][fk];
            #pragma unroll
            for (int m = 0; m < 4; ++m) {
                acc1[m][n] = __builtin_amdgcn_mfma_f32_16x16x32_bf16(af[m], w1f, acc1[m][n], 0, 0, 0);
                acc2[m][n] = __builtin_amdgcn_mfma_f32_16x16x32_bf16(af[m], w2f, acc2[m][n], 0, 0, 0);
            }
        }
    }

    const int rj = (lane >> 4) * 4;
    #pragma unroll
    for (int m = 0; m < 4; ++m) {
        #pragma unroll
        for (int j = 0; j < 4; ++j) {
            const size_t row = (size_t)(bm + wr * 64 + m * 16 + rj + j);
            #pragma unroll
            for (int n = 0; n < 4; ++n) {
                const size_t col = (size_t)(bn + wc * 64 + n * 16 + fr);
                float a1 = acc1[m][n][j];
                float a2 = acc2[m][n][j];
                float sv = (a1 / (1.0f + __expf(-a1))) * a2;
                ((unsigned short*)Mo)[row * N + col] = f2bf(sv);
            }
        }
    }
}

// ============================ MFMA flash attention ============================
// Block: 4 waves, 128 q-rows (wave w owns rows w*32..+31). KV tiles of 64.
// Q in registers (A-frags). K row-major LDS [64][128] (=B^T for QK^T).
// V transposed LDS [128][64] (=B^T for PV). P via LDS [128][64] (C/D->A reshape).
// All LDS tiles XOR-swizzled: byte ^= (row&7)<<4 (write and read sides).
#define AQB 128
#define AKV 64

__global__ __launch_bounds__(256) void attn_mfma(const __hip_bfloat16* __restrict__ q,
        const __hip_bfloat16* __restrict__ k, const __hip_bfloat16* __restrict__ v,
        __hip_bfloat16* __restrict__ y)
{
    __shared__ alignas(16) unsigned short Ks[AKV * HDIM];   // [j][d]  16KB
    __shared__ alignas(16) unsigned short Vt[HDIM * AKV];   // [d][j]  16KB
    __shared__ alignas(16) unsigned short Ps[AQB * AKV];    // [r][j]  16KB

    const int qt = (TT / AQB - 1) - blockIdx.x;   // heavy blocks first
    const int h  = blockIdx.y;
    const int b  = blockIdx.z;
    const int g  = h >> 2;
    const int qbase = qt * AQB;

    const int tid  = threadIdx.x;
    const int lane = tid & 63;
    const int wid  = tid >> 6;
    const int fr   = lane & 15;
    const int fk8  = (lane >> 4) * 8;
    const int rj   = (lane >> 4) * 4;

    // ---- Q fragments in registers ----
    bf8 qf[2][4];
    {
        const unsigned short* qp = (const unsigned short*)q;
        #pragma unroll
        for (int m = 0; m < 2; ++m) {
            const size_t row = (size_t)(b * TT + qbase + wid * 32 + m * 16 + fr);
            #pragma unroll
            for (int c = 0; c < 4; ++c)
                qf[m][c] = *(const bf8*)(qp + row * CC + h * HDIM + c * 32 + fk8);
        }
    }

    f32x4 oacc[2][8];
    float m_r[2][4], l_r[2][4];
    #pragma unroll
    for (int m = 0; m < 2; ++m) {
        #pragma unroll
        for (int n = 0; n < 8; ++n) oacc[m][n] = (f32x4){0.f, 0.f, 0.f, 0.f};
        #pragma unroll
        for (int j = 0; j < 4; ++j) { m_r[m][j] = -1e30f; l_r[m][j] = 0.f; }
    }

    const float scale = 0.08838834764831845f;   // 1/sqrt(128)
    const int ntiles = qbase / AKV + 2;
    const int jr = tid >> 2;            // staging row 0..63
    const int kc = (tid & 3) * 32;      // staging col chunk

    for (int tile = 0; tile < ntiles; ++tile) {
        const int jbase = tile * AKV;
        __syncthreads();   // previous tile reads done
        // ---- stage K (row-major, swz) and V (transposed, swz) ----
        {
            const unsigned short* kp = (const unsigned short*)k + ((size_t)(b * TT + jbase + jr) * (NKV * HDIM)) + g * HDIM + kc;
            const unsigned short* vp = (const unsigned short*)v + ((size_t)(b * TT + jbase + jr) * (NKV * HDIM)) + g * HDIM + kc;
            #pragma unroll
            for (int c = 0; c < 4; ++c) {
                u16x8 kv = *(const u16x8*)(kp + c * 8);
                const int byteK = (jr * 256 + (kc + c * 8) * 2) ^ ((jr & 7) << 4);
                *(u16x8*)((char*)Ks + byteK) = kv;
                u16x8 vv = *(const u16x8*)(vp + c * 8);
                #pragma unroll
                for (int e = 0; e < 8; ++e) {
                    const int d = kc + c * 8 + e;
                    const int byteV = (d * 128 + jr * 2) ^ ((d & 7) << 4);
                    *(unsigned short*)((char*)Vt + byteV) = vv[e];
                }
            }
        }
        __syncthreads();

        // ---- S = Q K^T ----
        f32x4 s[2][4];
        #pragma unroll
        for (int m = 0; m < 2; ++m)
            #pragma unroll
            for (int n = 0; n < 4; ++n) s[m][n] = (f32x4){0.f, 0.f, 0.f, 0.f};
        #pragma unroll
        for (int c = 0; c < 4; ++c) {
            #pragma unroll
            for (int n = 0; n < 4; ++n) {
                const int j = n * 16 + fr;
                const int byteB = (j * 256 + (c * 32 + fk8) * 2) ^ ((j & 7) << 4);
                bf8 kf = *(const bf8*)((char*)Ks + byteB);
                s[0][n] = __builtin_amdgcn_mfma_f32_16x16x32_bf16(qf[0][c], kf, s[0][n], 0, 0, 0);
                s[1][n] = __builtin_amdgcn_mfma_f32_16x16x32_bf16(qf[1][c], kf, s[1][n], 0, 0, 0);
            }
        }

        // ---- online softmax + P -> LDS (wave-private region, no barrier) ----
        #pragma unroll
        for (int m = 0; m < 2; ++m) {
            #pragma unroll
            for (int jj = 0; jj < 4; ++jj) {
                const int qg = qbase + wid * 32 + m * 16 + rj + jj;
                float sv[4];
                #pragma unroll
                for (int n = 0; n < 4; ++n) {
                    const int jg = jbase + n * 16 + fr;
                    sv[n] = (jg <= qg) ? s[m][n][jj] * scale : -1e30f;
                }
                float tmax = fmaxf(fmaxf(sv[0], sv[1]), fmaxf(sv[2], sv[3]));
                tmax = fmaxf(tmax, __shfl_xor(tmax, 1));
                tmax = fmaxf(tmax, __shfl_xor(tmax, 2));
                tmax = fmaxf(tmax, __shfl_xor(tmax, 4));
                tmax = fmaxf(tmax, __shfl_xor(tmax, 8));
                const float mnew = fmaxf(m_r[m][jj], tmax);
                const float alpha = __expf(m_r[m][jj] - mnew);
                m_r[m][jj] = mnew;
                const int prow = wid * 32 + m * 16 + rj + jj;
                float tsum = 0.f;
                #pragma unroll
                for (int n = 0; n < 4; ++n) {
                    const float p = __expf(sv[n] - mnew);
                    tsum += p;
                    const int byteP = (prow * 128 + (n * 16 + fr) * 2) ^ ((prow & 7) << 4);
                    *(unsigned short*)((char*)Ps + byteP) = f2bf(p);
                }
                tsum += __shfl_xor(tsum, 1);
                tsum += __shfl_xor(tsum, 2);
                tsum += __shfl_xor(tsum, 4);
                tsum += __shfl_xor(tsum, 8);
                l_r[m][jj] = l_r[m][jj] * alpha + tsum;
                #pragma unroll
                for (int n = 0; n < 8; ++n) oacc[m][n][jj] *= alpha;
            }
        }

        // ---- O += P V ----
        #pragma unroll
        for (int c2 = 0; c2 < 2; ++c2) {
            bf8 pf[2];
            #pragma unroll
            for (int m = 0; m < 2; ++m) {
                const int prow = wid * 32 + m * 16 + fr;
                const int byteA = (prow * 128 + (c2 * 32 + fk8) * 2) ^ ((prow & 7) << 4);
                pf[m] = *(const bf8*)((char*)Ps + byteA);
            }
            #pragma unroll
            for (int n = 0; n < 8; ++n) {
                const int d = n * 16 + fr;
                const int byteB = (d * 128 + (c2 * 32 + fk8) * 2) ^ ((d & 7) << 4);
                bf8 vf = *(const bf8*)((char*)Vt + byteB);
                oacc[0][n] = __builtin_amdgcn_mfma_f32_16x16x32_bf16(pf[0], vf, oacc[0][n], 0, 0, 0);
                oacc[1][n] = __builtin_amdgcn_mfma_f32_16x16x32_bf16(pf[1], vf, oacc[1][n], 0, 0, 0);
            }
        }
    }

    // ---- epilogue ----
    #pragma unroll
    for (int m = 0; m < 2; ++m) {
        #pragma unroll
        for (int jj = 0; jj < 4; ++jj) {
            const float inv = 1.0f / l_r[m][jj];
            unsigned short* yrow = (unsigned short*)y + ((size_t)(b * TT + qbase + wid * 32 + m * 16 + rj + jj) * CC) + h * HDIM;
            #pragma unroll
            for (int n = 0; n < 8; ++n)
                yrow[n * 16 + fr] = f2bf(oacc[m][n][jj] * inv);
        }
    }
}

// ============================ launch ============================
extern "C" void kernel_launch(void* const* d_in, const int* in_sizes, int n_in,
                              void* d_out, int out_size, void* d_ws, size_t ws_size,
                              hipStream_t stream)
{
    (void)in_sizes; (void)n_in; (void)out_size; (void)ws_size;
    const float* x     = (const float*)d_in[0];
    const float* fc    = (const float*)d_in[1];
    const float* wq    = (const float*)d_in[2];
    const float* wk    = (const float*)d_in[3];
    const float* wv    = (const float*)d_in[4];
    const float* wo    = (const float*)d_in[5];
    const float* w1    = (const float*)d_in[6];
    const float* w2    = (const float*)d_in[7];
    const float* cproj = (const float*)d_in[8];
    const float* g1    = (const float*)d_in[9];
    const float* g2    = (const float*)d_in[10];
    float* out = (float*)d_out;

    const int ROWS = NB * TT;  // 4096
    unsigned char* wsb = (unsigned char*)d_ws;
    __hip_bfloat16* x2b = (__hip_bfloat16*)(wsb);
    __hip_bfloat16* hb  = (__hip_bfloat16*)(wsb + (16u << 20));
    unsigned char* S1 = wsb + (32u << 20);
    unsigned char* S2 = wsb + (32u << 20) + 46137344u;
    // phase A views of S1: qb 16MB | kb 4MB @16M | vb 4MB @20M | yb 16MB @24M
    __hip_bfloat16* qb = (__hip_bfloat16*)(S1);
    __hip_bfloat16* kb = (__hip_bfloat16*)(S1 + (16u << 20));
    __hip_bfloat16* vb = (__hip_bfloat16*)(S1 + (20u << 20));
    __hip_bfloat16* yb = (__hip_bfloat16*)(S1 + (24u << 20));
    // phase B views of S1
    __hip_bfloat16* w1b = (__hip_bfloat16*)(S1);
    __hip_bfloat16* w2b = (__hip_bfloat16*)(S1 + 23068672u);
    __hip_bfloat16* cpb = (__hip_bfloat16*)(S1);
    // S2: phase A = weight scratch (qkv/wo), phase B = FFN activation
    __hip_bfloat16* wbuf = (__hip_bfloat16*)(S2);
    __hip_bfloat16* mbb  = (__hip_bfloat16*)(S2);

    // 1. h = rmsnorm(x)*g1
    rms_f32_k<<<ROWS, 256, 0, stream>>>(x, g1, hb);
    // 2. q/k/v projections
    cvt_k<<<(CC * CC) / 2048, 256, 0, stream>>>(wq, wbuf);
    gemm_mfma<0, 1><<<dim3(CC / GBN, ROWS / GBM), 256, 0, stream>>>(hb, wbuf, nullptr, qb, ROWS, CC, CC);
    cvt_k<<<(NKV * HDIM * CC) / 2048, 256, 0, stream>>>(wk, wbuf);
    gemm_mfma<0, 1><<<dim3((NKV * HDIM) / GBN, ROWS / GBM), 256, 0, stream>>>(hb, wbuf, nullptr, kb, ROWS, NKV * HDIM, CC);
    cvt_k<<<(NKV * HDIM * CC) / 2048, 256, 0, stream>>>(wv, wbuf);
    gemm_mfma<0, 1><<<dim3((NKV * HDIM) / GBN, ROWS / GBM), 256, 0, stream>>>(hb, wbuf, nullptr, vb, ROWS, NKV * HDIM, CC);
    // 3. RoPE
    rope_k<<<(ROWS * NH * 64) / 256, 256, 0, stream>>>(qb, fc, NH);
    rope_k<<<(ROWS * NKV * 64) / 256, 256, 0, stream>>>(kb, fc, NKV);
    // 4. attention (MFMA)
    attn_mfma<<<dim3(TT / AQB, NH, NB), 256, 0, stream>>>(qb, kb, vb, yb);
    // 5. x2 = bf16(x + y @ wo^T)
    cvt_k<<<(CC * CC) / 2048, 256, 0, stream>>>(wo, wbuf);
    gemm_mfma<1, 1><<<dim3(CC / GBN, ROWS / GBM), 256, 0, stream>>>(yb, wbuf, x, x2b, ROWS, CC, CC);
    // 6. h2 = rmsnorm(x2)*g2
    rms_bf16_k<<<ROWS, 256, 0, stream>>>(x2b, g2, hb);
    // 7. m = bf16(silu(h2@w1^T) * (h2@w2^T))
    cvt_k<<<(NFFN * CC) / 2048, 256, 0, stream>>>(w1, w1b);
    cvt_k<<<(NFFN * CC) / 2048, 256, 0, stream>>>(w2, w2b);
    gemm_ffn_mfma<<<dim3(NFFN / GBN, ROWS / GBM), 256, 0, stream>>>(hb, w1b, w2b, mbb, ROWS, NFFN, CC);
    // 8. out = x2 + m @ cproj^T  (f32)
    cvt_k<<<(CC * NFFN) / 2048, 256, 0, stream>>>(cproj, cpb);
    gemm_mfma<2, 0><<<dim3(CC / GBN, ROWS / GBM), 256, 0, stream>>>(mbb, cpb, x2b, out, ROWS, CC, NFFN);
}